// Round 11
// baseline (54.554 us; speedup 1.0000x reference)
//
#include <hip/hip_runtime.h>
#include <stdint.h>

#define B 4
#define N 16384
#define S 2048
#define C 64
#define K 64
#define OC 66
#define R2 0.01f
#define NXCD 8

typedef float f32x4 __attribute__((ext_vector_type(4)));

// ---------------------------------------------------------------------------
// Kernel 1: transpose features (B,C,N) -> ft (B,N,C).
// ---------------------------------------------------------------------------
__global__ __launch_bounds__(256) void transpose_kernel(const float* __restrict__ f,
                                                        float* __restrict__ ft) {
    __shared__ float tile[64 * 65];
    const int n0 = blockIdx.x * 64;
    const int b  = blockIdx.y;
    const int t  = threadIdx.x;

    const int nl = t & 63, cl = t >> 6;
    #pragma unroll
    for (int cc = cl; cc < 64; cc += 4) {
        tile[cc * 65 + nl] = __builtin_nontemporal_load(&f[((size_t)b * C + cc) * N + n0 + nl]);
    }
    __syncthreads();

    const int cl2 = t & 63, nl2 = t >> 6;
    #pragma unroll
    for (int nn = nl2; nn < 64; nn += 4) {
        ft[((size_t)b * N + n0 + nn) * C + cl2] = tile[cl2 * 65 + nn];
    }
}

// ---------------------------------------------------------------------------
// Kernel 2: fused ball-query + group + concat. R9 structure (zero barriers,
// cached stores, XCD swizzle, prefetched scan) with ONE change: phase 2
// stores DIRECTLY from gather registers — no LDS roundtrip. Lane (kk,c2)
// gathers f32x4 of point g*16+kk, chunk-slot c2, and writes 4 scalar stores
// to 4 channel planes; per plane a wave covers 16 consecutive k = 64B
// fully-used runs. Removes the ds_write->ds_read->store dependency chain.
// ---------------------------------------------------------------------------
__global__ __launch_bounds__(256) void qag4_kernel(const float* __restrict__ xyz,
                                                   const float* __restrict__ new_xyz,
                                                   const float* __restrict__ ft,
                                                   const int* __restrict__ pointsnum,
                                                   float* __restrict__ out) {
    __shared__ int s_idx[4][K];            // per-wave index list (1 KB)

    const int t    = threadIdx.x;
    const int lane = t & 63;
    const int wu   = __builtin_amdgcn_readfirstlane(t >> 6);

    // bijective XCD swizzle: nwg = 2048, 2048 % 8 == 0
    const int nwg = (B * S) / 4;
    const int bid = blockIdx.x;
    const int swz = (bid & (NXCD - 1)) * (nwg / NXCD) + (bid >> 3);

    const int q0 = swz * 4;
    const int b  = q0 >> 11;               // / S
    const int q  = q0 + wu;
    const int s  = (q0 & (S - 1)) + wu;

    const float qx = new_xyz[(size_t)q * 2 + 0];
    const float qy = new_xyz[(size_t)q * 2 + 1];
    const float* __restrict__ xb = xyz + (size_t)b * N * 2;

    // ---- Phase 1: ordered ball-query scan, next-chunk prefetch ----
    int pn = pointsnum[b];
    pn = pn < 0 ? 0 : (pn > N ? N : pn);
    int cnt = 0;
    float2 p[4], pf[4];
    #pragma unroll
    for (int u = 0; u < 4; ++u) {
        const int i  = u * 64 + lane;
        const int ic = i < N ? i : N - 1;
        p[u] = *(const float2*)&xb[(size_t)ic * 2];
    }
    for (int base = 0; base < pn && cnt < K; base += 256) {
        #pragma unroll
        for (int u = 0; u < 4; ++u) {       // prefetch next super-chunk
            const int i  = base + 256 + u * 64 + lane;
            const int ic = i < N ? i : N - 1;
            pf[u] = *(const float2*)&xb[(size_t)ic * 2];
        }
        #pragma unroll
        for (int u = 0; u < 4; ++u) {
            const int i = base + u * 64 + lane;
            bool ok = false;
            if (i < pn) {
                // match numpy f32 rounding exactly: no FMA contraction
                const float dx = __fsub_rn(qx, p[u].x);
                const float dy = __fsub_rn(qy, p[u].y);
                const float d2 = __fadd_rn(__fmul_rn(dx, dx), __fmul_rn(dy, dy));
                ok = d2 < R2;
            }
            const unsigned long long m = __ballot(ok);
            if (ok) {
                const int pos = cnt + __popcll(m & ((1ull << lane) - 1ull));
                if (pos < K) s_idx[wu][pos] = i;
            }
            cnt += __popcll(m);
        }
        #pragma unroll
        for (int u = 0; u < 4; ++u) p[u] = pf[u];
    }
    const int found = cnt < K ? cnt : K;
    const int first = (found > 0) ? s_idx[wu][0] : 0;
    const int id    = (lane < found) ? s_idx[wu][lane] : first;
    s_idx[wu][lane] = id;                  // padded list (same-wave use only)

    // ---- channels 0,1: grouped_xyz = xyz[id] - new_xyz[s] ----
    const size_t SK = (size_t)S * K;
    const float2 pxy = *(const float2*)&xb[(size_t)id * 2];
    float* ob = out + ((size_t)b * OC) * SK + (size_t)s * K;
    ob[lane]      = pxy.x - qx;
    ob[SK + lane] = pxy.y - qy;

    // ---- Phase 2: gather (4 lanes/row) -> direct register stores ----
    const int kk = lane >> 2;              // point sub-index 0..15
    const int c2 = lane & 3;               // float4 slot within 16-ch chunk
    const float* __restrict__ ftb = ft + (size_t)b * N * C;

    int ids[4];
    #pragma unroll
    for (int g = 0; g < 4; ++g) ids[g] = s_idx[wu][g * 16 + kk];

    #pragma unroll
    for (int cc = 0; cc < 4; ++cc) {       // 16-channel chunks
        f32x4 v[4];
        #pragma unroll
        for (int g = 0; g < 4; ++g) {      // 16 rows x full 64B line per instr
            v[g] = *(const f32x4*)&ftb[(size_t)ids[g] * C + cc * 16 + c2 * 4];
        }
        #pragma unroll
        for (int g = 0; g < 4; ++g) {
            const int k = g * 16 + kk;
            const size_t cb = (size_t)(2 + cc * 16 + c2 * 4) * SK + k;
            ob[cb]          = v[g].x;      // per plane: 16 lanes x 4B = 64B run
            ob[cb + SK]     = v[g].y;
            ob[cb + 2 * SK] = v[g].z;
            ob[cb + 3 * SK] = v[g].w;
        }
    }
}

// ---------------------------------------------------------------------------
// Fallback (tiny ws): fused kernel gathering directly from (B,C,N) feat.
// ---------------------------------------------------------------------------
__global__ __launch_bounds__(256) void qag_fallback(const float* __restrict__ xyz,
                                                    const float* __restrict__ new_xyz,
                                                    const float* __restrict__ feat,
                                                    const int* __restrict__ pointsnum,
                                                    float* __restrict__ out) {
    __shared__ int s_idx[4][K];

    const int t    = threadIdx.x;
    const int lane = t & 63;
    const int wu   = __builtin_amdgcn_readfirstlane(t >> 6);
    const int q0   = blockIdx.x * 4;
    const int b    = q0 >> 11;
    const int q    = q0 + wu;
    const int s    = (q0 & (S - 1)) + wu;

    const float qx = new_xyz[(size_t)q * 2 + 0];
    const float qy = new_xyz[(size_t)q * 2 + 1];
    const float* __restrict__ xb = xyz + (size_t)b * N * 2;

    int pn = pointsnum[b];
    pn = pn < 0 ? 0 : (pn > N ? N : pn);
    int cnt = 0;
    for (int base = 0; base < pn && cnt < K; base += 256) {
        float2 p[4];
        #pragma unroll
        for (int u = 0; u < 4; ++u) {
            int i  = base + u * 64 + lane;
            int ic = i < N ? i : N - 1;
            p[u] = *(const float2*)&xb[(size_t)ic * 2];
        }
        #pragma unroll
        for (int u = 0; u < 4; ++u) {
            const int i = base + u * 64 + lane;
            bool ok = false;
            if (i < pn) {
                const float dx = __fsub_rn(qx, p[u].x);
                const float dy = __fsub_rn(qy, p[u].y);
                const float d2 = __fadd_rn(__fmul_rn(dx, dx), __fmul_rn(dy, dy));
                ok = d2 < R2;
            }
            const unsigned long long mm = __ballot(ok);
            if (ok) {
                const int pos = cnt + __popcll(mm & ((1ull << lane) - 1ull));
                if (pos < K) s_idx[wu][pos] = i;
            }
            cnt += __popcll(mm);
        }
    }
    const int found = cnt < K ? cnt : K;
    const int first = (found > 0) ? s_idx[wu][0] : 0;
    const int id    = (lane < found) ? s_idx[wu][lane] : first;

    const size_t SK = (size_t)S * K;
    const float2 pxy = *(const float2*)&xb[(size_t)id * 2];
    float* ob = out + ((size_t)b * OC) * SK + (size_t)s * K;
    ob[lane]      = pxy.x - qx;
    ob[SK + lane] = pxy.y - qy;

    const float* __restrict__ fb = feat + (size_t)b * C * N;
    for (int c = 0; c < C; ++c) {
        ob[(size_t)(2 + c) * SK + lane] = fb[(size_t)c * N + id];
    }
}

extern "C" void kernel_launch(void* const* d_in, const int* in_sizes, int n_in,
                              void* d_out, int out_size, void* d_ws, size_t ws_size,
                              hipStream_t stream) {
    const float* xyz       = (const float*)d_in[0];
    const float* new_xyz   = (const float*)d_in[1];
    const float* feat      = (const float*)d_in[2];
    const int*   pointsnum = (const int*)d_in[3];
    float*       out       = (float*)d_out;

    const size_t ft_bytes = (size_t)B * N * C * sizeof(float);    // 16.8 MB
    if (ws_size >= ft_bytes) {
        float* ft = (float*)d_ws;
        transpose_kernel<<<dim3(N / 64, B), 256, 0, stream>>>(feat, ft);
        qag4_kernel<<<B * S / 4, 256, 0, stream>>>(xyz, new_xyz, ft, pointsnum, out);
    } else {
        qag_fallback<<<B * S / 4, 256, 0, stream>>>(xyz, new_xyz, feat, pointsnum, out);
    }
}